// Round 1
// baseline (86.461 us; speedup 1.0000x reference)
//
#include <hip/hip_runtime.h>

typedef __attribute__((ext_vector_type(8))) short bf16x8;
typedef __attribute__((ext_vector_type(4))) float f32x4;

#define BATCH 8
#define SEQ 2048
#define DIM 64
#define QBLK 32
#define KVBLK 64

__device__ __forceinline__ short f2bf(float f) {
    unsigned u = __builtin_bit_cast(unsigned, f);
    unsigned r = (u + 0x7FFFu + ((u >> 16) & 1u)) >> 16;
    return (short)r;
}

__global__ __launch_bounds__(128) void fa_kernel(const float* __restrict__ Q,
                                                 const float* __restrict__ K,
                                                 const float* __restrict__ V,
                                                 float* __restrict__ O) {
    __shared__ short Klds[KVBLK * DIM];       // [kv][d], swizzled
    __shared__ short Vlds[DIM * KVBLK];       // [d][kv] (transposed), swizzled
    __shared__ short Plds[2][16 * KVBLK];     // per-wave P tile, swizzled

    const int tid = threadIdx.x;
    const int w = tid >> 6;          // wave id 0/1
    const int lane = tid & 63;
    const int g = lane >> 4;         // 4-group
    const int c = lane & 15;

    // block -> (batch, q-tile) with complementary pairing for causal balance
    int b = blockIdx.x;
    int h = b >> 1;
    int p = h & 31;
    int batch = h >> 5;
    int qi = (b & 1) ? (63 - p) : p;
    int q0 = qi * QBLK;

    // Q A-fragments, pre-scaled by 1/8 (row = lane&15, k = g*8+j)
    const float* Qrow = Q + (size_t)(batch * SEQ + q0 + w * 16 + c) * DIM;
    bf16x8 qa[2];
    #pragma unroll
    for (int f = 0; f < 2; ++f) {
        #pragma unroll
        for (int j = 0; j < 8; ++j)
            qa[f][j] = f2bf(Qrow[f * 32 + g * 8 + j] * 0.125f);
    }

    float m[4], l[4];
    f32x4 o[4];
    #pragma unroll
    for (int r = 0; r < 4; ++r) { m[r] = -1e30f; l[r] = 0.f; }
    #pragma unroll
    for (int dt = 0; dt < 4; ++dt) o[dt] = f32x4{0.f, 0.f, 0.f, 0.f};

    const int niter = ((q0 + QBLK - 1) >> 6) + 1;
    const float* Kb0 = K + (size_t)batch * SEQ * DIM;
    const float* Vb0 = V + (size_t)batch * SEQ * DIM;

    for (int it = 0; it < niter; ++it) {
        const int kv0 = it * KVBLK;
        __syncthreads();
        // ---- stage K (row-major) and V (transposed) as bf16, swizzled ----
        const float* Kt = Kb0 + (size_t)kv0 * DIM;
        const float* Vt = Vb0 + (size_t)kv0 * DIM;
        #pragma unroll
        for (int i = 0; i < 8; ++i) {
            int idx = i * 128 + tid;
            int row = idx >> 4;            // kv row 0..63
            int d0 = (idx & 15) << 2;      // d 0..60 step 4
            float4 kf = *(const float4*)(Kt + row * DIM + d0);
            short4 kb4 = make_short4(f2bf(kf.x), f2bf(kf.y), f2bf(kf.z), f2bf(kf.w));
            int e = (row * DIM + d0) ^ ((row & 7) << 3);
            *(short4*)(&Klds[e]) = kb4;
            float4 vf = *(const float4*)(Vt + row * DIM + d0);
            float vv[4] = {vf.x, vf.y, vf.z, vf.w};
            #pragma unroll
            for (int jj = 0; jj < 4; ++jj) {
                int d = d0 + jj;
                int e2 = (d * KVBLK + row) ^ ((d & 7) << 3);
                Vlds[e2] = f2bf(vv[jj]);
            }
        }
        __syncthreads();

        // ---- QK^T: S[16 q][64 kv] per wave ----
        f32x4 s[4];
        #pragma unroll
        for (int n = 0; n < 4; ++n) {
            s[n] = f32x4{0.f, 0.f, 0.f, 0.f};
            #pragma unroll
            for (int f = 0; f < 2; ++f) {
                int row = n * 16 + c;
                int e = (row * DIM + f * 32 + g * 8) ^ ((row & 7) << 3);
                bf16x8 kb = *(bf16x8*)(&Klds[e]);
                s[n] = __builtin_amdgcn_mfma_f32_16x16x32_bf16(qa[f], kb, s[n], 0, 0, 0);
            }
        }

        // ---- causal mask (last tile only) ----
        if (it == niter - 1) {
            #pragma unroll
            for (int n = 0; n < 4; ++n) {
                int col = kv0 + n * 16 + c;
                #pragma unroll
                for (int r = 0; r < 4; ++r) {
                    int qrow = q0 + w * 16 + g * 4 + r;
                    if (col > qrow) s[n][r] = -1e30f;
                }
            }
        }

        // ---- online softmax (rows live on 16-lane groups) ----
        float alpha[4];
        #pragma unroll
        for (int r = 0; r < 4; ++r) {
            float t = fmaxf(fmaxf(s[0][r], s[1][r]), fmaxf(s[2][r], s[3][r]));
            t = fmaxf(t, __shfl_xor(t, 1));
            t = fmaxf(t, __shfl_xor(t, 2));
            t = fmaxf(t, __shfl_xor(t, 4));
            t = fmaxf(t, __shfl_xor(t, 8));
            float mn = fmaxf(m[r], t);
            alpha[r] = __expf(m[r] - mn);
            m[r] = mn;
        }
        float tsum[4] = {0.f, 0.f, 0.f, 0.f};
        #pragma unroll
        for (int n = 0; n < 4; ++n) {
            #pragma unroll
            for (int r = 0; r < 4; ++r) {
                float pe = __expf(s[n][r] - m[r]);
                s[n][r] = pe;
                tsum[r] += pe;
            }
        }
        #pragma unroll
        for (int r = 0; r < 4; ++r) {
            float ts = tsum[r];
            ts += __shfl_xor(ts, 1);
            ts += __shfl_xor(ts, 2);
            ts += __shfl_xor(ts, 4);
            ts += __shfl_xor(ts, 8);
            l[r] = l[r] * alpha[r] + ts;
        }
        #pragma unroll
        for (int dt = 0; dt < 4; ++dt) {
            #pragma unroll
            for (int r = 0; r < 4; ++r)
                o[dt][r] *= alpha[r];
        }

        // ---- P (C-layout) -> LDS -> A-layout ----
        short* Pw = &Plds[w][0];
        #pragma unroll
        for (int n = 0; n < 4; ++n) {
            #pragma unroll
            for (int r = 0; r < 4; ++r) {
                int row = g * 4 + r;
                int e = (row * KVBLK + n * 16 + c) ^ ((row & 7) << 3);
                Pw[e] = f2bf(s[n][r]);
            }
        }
        asm volatile("s_waitcnt lgkmcnt(0)" ::: "memory");

        // ---- PV: O[16 q][64 d] += P[16][64] * V[64][64] ----
        #pragma unroll
        for (int ks = 0; ks < 2; ++ks) {
            int e = (c * KVBLK + ks * 32 + g * 8) ^ ((c & 7) << 3);
            bf16x8 pa = *(bf16x8*)(&Pw[e]);
            #pragma unroll
            for (int dt = 0; dt < 4; ++dt) {
                int d = dt * 16 + c;
                int e2 = (d * KVBLK + ks * 32 + g * 8) ^ ((d & 7) << 3);
                bf16x8 vb = *(bf16x8*)(&Vlds[e2]);
                o[dt] = __builtin_amdgcn_mfma_f32_16x16x32_bf16(pa, vb, o[dt], 0, 0, 0);
            }
        }
    }

    // ---- epilogue: divide by l, store fp32 ----
    #pragma unroll
    for (int r = 0; r < 4; ++r) {
        float inv = 1.f / l[r];
        int qrow = q0 + w * 16 + g * 4 + r;
        float* Orow = O + (size_t)(batch * SEQ + qrow) * DIM;
        #pragma unroll
        for (int dt = 0; dt < 4; ++dt)
            Orow[dt * 16 + c] = o[dt][r] * inv;
    }
}

extern "C" void kernel_launch(void* const* d_in, const int* in_sizes, int n_in,
                              void* d_out, int out_size, void* d_ws, size_t ws_size,
                              hipStream_t stream) {
    const float* Q = (const float*)d_in[0];
    const float* K = (const float*)d_in[1];
    const float* V = (const float*)d_in[2];
    float* O = (float*)d_out;
    (void)in_sizes; (void)n_in; (void)out_size; (void)d_ws; (void)ws_size;
    dim3 grid(BATCH * (SEQ / QBLK) / 2 * 2);  // 512 blocks
    dim3 block(128);
    fa_kernel<<<512, 128, 0, stream>>>(Q, K, V, O);
}

// Round 2
// 65.797 us; speedup vs baseline: 1.3141x; 1.3141x over previous
//
#include <hip/hip_runtime.h>

typedef __attribute__((ext_vector_type(8))) short bf16x8;
typedef __attribute__((ext_vector_type(4))) float f32x4;

#define BATCH 8
#define SEQ 2048
#define DIM 64
#define QBLK 32
#define KVBLK 64
#define NROWS (BATCH * SEQ)   // 16384

__device__ __forceinline__ short f2bf(float f) {
    unsigned u = __builtin_bit_cast(unsigned, f);
    unsigned r = (u + 0x7FFFu + ((u >> 16) & 1u)) >> 16;
    return (short)r;
}

// K tile [kv][d]: row-major, XOR-swizzled. Write short4 (lanes vary d) and
// read b128 (lanes vary row) both spread >=8 banks.
__device__ __forceinline__ int kswz(int row, int d) {
    return (row * DIM + d) ^ ((row & 7) << 3);
}
// V^T tile [d][kv]: writes are short4 along kv with lanes varying d at
// stride 4 (so need d>>2 in the hash); reads are b128 with lanes varying
// d at stride 1 (d&7 part). F(d) = (d&7)^((d>>2)&7) serves both.
__device__ __forceinline__ int vswz(int d, int kv) {
    return (d * KVBLK + kv) ^ ((((d & 7) ^ ((d >> 2) & 7)) & 7) << 3);
}
// P tile [row16][kv]: rows vary across g (stride 4) -> (row&7) hash is 2-way, fine.
__device__ __forceinline__ int pswz(int row, int kv) {
    return (row * KVBLK + kv) ^ ((row & 7) << 3);
}

__global__ __launch_bounds__(128) void fa_kernel(const float* __restrict__ Q,
                                                 const float* __restrict__ K,
                                                 const float* __restrict__ V,
                                                 float* __restrict__ PO,
                                                 float* __restrict__ PM,
                                                 float* __restrict__ PL,
                                                 float* __restrict__ O,
                                                 int splits) {
    __shared__ short Klds[KVBLK * DIM];
    __shared__ short Vlds[DIM * KVBLK];
    __shared__ short Plds[2][16 * KVBLK];

    const int tid = threadIdx.x;
    const int w = tid >> 6;
    const int lane = tid & 63;
    const int g = lane >> 4;
    const int c = lane & 15;

    // block -> (batch, q-tile, kv-chunk); big q-tiles dispatched first
    int idx = blockIdx.x;
    int sp = idx % splits;
    int h = idx / splits;
    int qi = 63 - (h & 63);
    int batch = h >> 6;
    int q0 = qi * QBLK;
    int nt = (qi >> 1) + 1;                 // causal KV tiles for this q-tile
    int csz = (nt + splits - 1) / splits;
    int t0 = sp * csz;
    int t1 = min(nt, t0 + csz);
    const int rowbase = batch * SEQ + q0;

    if (t0 >= t1) {  // empty chunk (only when splits>1): neutral partials
        for (int i = tid; i < QBLK * DIM; i += 128)
            PO[((size_t)sp * NROWS + rowbase) * DIM + i] = 0.f;
        if (tid < QBLK) {
            PM[(size_t)sp * NROWS + rowbase + tid] = -1e30f;
            PL[(size_t)sp * NROWS + rowbase + tid] = 0.f;
        }
        return;
    }

    // Q A-fragments, pre-scaled by 1/8
    const float* Qrow = Q + (size_t)(rowbase + w * 16 + c) * DIM;
    bf16x8 qa[2];
    #pragma unroll
    for (int f = 0; f < 2; ++f) {
        #pragma unroll
        for (int j = 0; j < 8; ++j)
            qa[f][j] = f2bf(Qrow[f * 32 + g * 8 + j] * 0.125f);
    }

    float m[4], l[4];
    f32x4 o[4];
    #pragma unroll
    for (int r = 0; r < 4; ++r) { m[r] = -1e30f; l[r] = 0.f; }
    #pragma unroll
    for (int dt = 0; dt < 4; ++dt) o[dt] = f32x4{0.f, 0.f, 0.f, 0.f};

    const float* Kb0 = K + (size_t)batch * SEQ * DIM;
    const float* Vb0 = V + (size_t)batch * SEQ * DIM;

    for (int t = t0; t < t1; ++t) {
        const int kv0 = t * KVBLK;
        __syncthreads();
        const float* Kt = Kb0 + (size_t)kv0 * DIM;
        const float* Vt = Vb0 + (size_t)kv0 * DIM;
        // ---- stage K row-major (vector writes) ----
        #pragma unroll
        for (int i = 0; i < 8; ++i) {
            int id2 = i * 128 + tid;
            int row = id2 >> 4;
            int d0 = (id2 & 15) << 2;
            float4 kf = *(const float4*)(Kt + row * DIM + d0);
            *(short4*)(&Klds[kswz(row, d0)]) =
                make_short4(f2bf(kf.x), f2bf(kf.y), f2bf(kf.z), f2bf(kf.w));
        }
        // ---- stage V^T via register 4x4 transpose (short4 writes along kv) ----
        #pragma unroll
        for (int i = 0; i < 2; ++i) {
            int tile = i * 128 + tid;      // 256 (4 kv x 4 d) tiles
            int dt4 = tile & 15;           // d-group: coalesced across lanes
            int k4 = tile >> 4;            // kv-group
            f32x4 vf[4];
            #pragma unroll
            for (int rr = 0; rr < 4; ++rr)
                vf[rr] = *(const f32x4*)(Vt + (k4 * 4 + rr) * DIM + dt4 * 4);
            #pragma unroll
            for (int dd = 0; dd < 4; ++dd) {
                int d = dt4 * 4 + dd;
                *(short4*)(&Vlds[vswz(d, k4 * 4)]) =
                    make_short4(f2bf(vf[0][dd]), f2bf(vf[1][dd]),
                                f2bf(vf[2][dd]), f2bf(vf[3][dd]));
            }
        }
        __syncthreads();

        // ---- QK^T: S[16 q][64 kv] per wave ----
        f32x4 s[4];
        #pragma unroll
        for (int n = 0; n < 4; ++n) {
            s[n] = f32x4{0.f, 0.f, 0.f, 0.f};
            #pragma unroll
            for (int f = 0; f < 2; ++f) {
                bf16x8 kb = *(bf16x8*)(&Klds[kswz(n * 16 + c, f * 32 + g * 8)]);
                s[n] = __builtin_amdgcn_mfma_f32_16x16x32_bf16(qa[f], kb, s[n], 0, 0, 0);
            }
        }

        // ---- causal mask (diagonal tile only) ----
        if (t == nt - 1) {
            #pragma unroll
            for (int n = 0; n < 4; ++n) {
                int col = kv0 + n * 16 + c;
                #pragma unroll
                for (int r = 0; r < 4; ++r) {
                    int qrow = q0 + w * 16 + g * 4 + r;
                    if (col > qrow) s[n][r] = -1e30f;
                }
            }
        }

        // ---- online softmax (rows live on 16-lane groups) ----
        float alpha[4];
        #pragma unroll
        for (int r = 0; r < 4; ++r) {
            float tmx = fmaxf(fmaxf(s[0][r], s[1][r]), fmaxf(s[2][r], s[3][r]));
            tmx = fmaxf(tmx, __shfl_xor(tmx, 1));
            tmx = fmaxf(tmx, __shfl_xor(tmx, 2));
            tmx = fmaxf(tmx, __shfl_xor(tmx, 4));
            tmx = fmaxf(tmx, __shfl_xor(tmx, 8));
            float mn = fmaxf(m[r], tmx);
            alpha[r] = __expf(m[r] - mn);
            m[r] = mn;
        }
        float tsum[4] = {0.f, 0.f, 0.f, 0.f};
        #pragma unroll
        for (int n = 0; n < 4; ++n) {
            #pragma unroll
            for (int r = 0; r < 4; ++r) {
                float pe = __expf(s[n][r] - m[r]);
                s[n][r] = pe;
                tsum[r] += pe;
            }
        }
        #pragma unroll
        for (int r = 0; r < 4; ++r) {
            float ts = tsum[r];
            ts += __shfl_xor(ts, 1);
            ts += __shfl_xor(ts, 2);
            ts += __shfl_xor(ts, 4);
            ts += __shfl_xor(ts, 8);
            l[r] = l[r] * alpha[r] + ts;
        }
        #pragma unroll
        for (int dt = 0; dt < 4; ++dt) {
            #pragma unroll
            for (int r = 0; r < 4; ++r)
                o[dt][r] *= alpha[r];
        }

        // ---- P (C-layout) -> LDS -> A-layout ----
        short* Pw = &Plds[w][0];
        #pragma unroll
        for (int n = 0; n < 4; ++n) {
            #pragma unroll
            for (int r = 0; r < 4; ++r)
                Pw[pswz(g * 4 + r, n * 16 + c)] = f2bf(s[n][r]);
        }
        asm volatile("s_waitcnt lgkmcnt(0)" ::: "memory");

        // ---- PV: O[16 q][64 d] += P[16][64] * V[64][64] ----
        #pragma unroll
        for (int ks = 0; ks < 2; ++ks) {
            bf16x8 pa = *(bf16x8*)(&Pw[pswz(c, ks * 32 + g * 8)]);
            #pragma unroll
            for (int dt = 0; dt < 4; ++dt) {
                bf16x8 vb = *(bf16x8*)(&Vlds[vswz(dt * 16 + c, ks * 32 + g * 8)]);
                o[dt] = __builtin_amdgcn_mfma_f32_16x16x32_bf16(pa, vb, o[dt], 0, 0, 0);
            }
        }
    }

    // ---- epilogue ----
    if (splits == 1) {
        #pragma unroll
        for (int r = 0; r < 4; ++r) {
            float inv = 1.f / l[r];
            float* Orow = O + (size_t)(rowbase + w * 16 + g * 4 + r) * DIM;
            #pragma unroll
            for (int dt = 0; dt < 4; ++dt)
                Orow[dt * 16 + c] = o[dt][r] * inv;
        }
    } else {
        #pragma unroll
        for (int r = 0; r < 4; ++r) {
            int qrow = rowbase + w * 16 + g * 4 + r;
            float* Prow = PO + ((size_t)sp * NROWS + qrow) * DIM;
            #pragma unroll
            for (int dt = 0; dt < 4; ++dt)
                Prow[dt * 16 + c] = o[dt][r];
            if (c == 0) {
                PM[(size_t)sp * NROWS + qrow] = m[r];
                PL[(size_t)sp * NROWS + qrow] = l[r];
            }
        }
    }
}

__global__ __launch_bounds__(256) void combine_kernel(const float* __restrict__ PO,
                                                      const float* __restrict__ PM,
                                                      const float* __restrict__ PL,
                                                      float* __restrict__ O,
                                                      int splits) {
    int row = blockIdx.x * 4 + (threadIdx.x >> 6);
    int d = threadIdx.x & 63;
    float mstar = -1e30f;
    for (int sp = 0; sp < splits; ++sp)
        mstar = fmaxf(mstar, PM[(size_t)sp * NROWS + row]);
    float lsum = 0.f, osum = 0.f;
    for (int sp = 0; sp < splits; ++sp) {
        float wgt = __expf(PM[(size_t)sp * NROWS + row] - mstar);
        lsum += PL[(size_t)sp * NROWS + row] * wgt;
        osum += PO[((size_t)sp * NROWS + row) * DIM + d] * wgt;
    }
    O[(size_t)row * DIM + d] = osum / lsum;
}

extern "C" void kernel_launch(void* const* d_in, const int* in_sizes, int n_in,
                              void* d_out, int out_size, void* d_ws, size_t ws_size,
                              hipStream_t stream) {
    const float* Q = (const float*)d_in[0];
    const float* K = (const float*)d_in[1];
    const float* V = (const float*)d_in[2];
    float* O = (float*)d_out;
    (void)in_sizes; (void)n_in; (void)out_size;

    const size_t R = NROWS;
    int splits = 1;
    const int cand[3] = {8, 4, 2};
    for (int i = 0; i < 3; ++i) {
        size_t need = (size_t)cand[i] * R * (DIM + 2) * sizeof(float);
        if (ws_size >= need) { splits = cand[i]; break; }
    }
    float* wo = (float*)d_ws;
    float* wm = wo + (size_t)splits * R * DIM;
    float* wl = wm + (size_t)splits * R;

    fa_kernel<<<dim3(512 * splits), dim3(128), 0, stream>>>(Q, K, V, wo, wm, wl, O, splits);
    if (splits > 1)
        combine_kernel<<<dim3((int)(R / 4)), dim3(256), 0, stream>>>(wo, wm, wl, O, splits);
}

// Round 3
// 63.238 us; speedup vs baseline: 1.3672x; 1.0405x over previous
//
#include <hip/hip_runtime.h>
#include <hip/hip_bf16.h>

typedef __attribute__((ext_vector_type(8))) short bf16x8;
typedef __attribute__((ext_vector_type(4))) float f32x4;
typedef __attribute__((ext_vector_type(4))) unsigned short us4;

#define BATCH 8
#define SEQ 2048
#define DIM 64
#define QB 64                 // q rows per block (4 waves x 16)
#define KB 64                 // kv rows per tile
#define NQT (SEQ / QB)        // 32
#define NKT (SEQ / KB)        // 32
#define TILE_ELEMS (KB * DIM) // 4096
#define NROWS (BATCH * SEQ)
#define QSCALE (0.125f * 1.44269504088896f)  // 1/sqrt(64) * log2(e)
#define THR 8.0f

__device__ __forceinline__ unsigned short f2bf(float f) {
    return __builtin_bit_cast(unsigned short, __float2bfloat16(f));
}

// K tile [kv][d] row-major, XOR-swizzled
__device__ __forceinline__ int kswz(int row, int d) {
    return (row * DIM + d) ^ ((row & 7) << 3);
}
// V^T tile [d][kv]; hash mixes d&7 and d>>2 so both short4 writes (lanes vary
// d by 4) and b128 reads (lanes vary d by 1) spread banks
__device__ __forceinline__ int vswz(int d, int kv) {
    return (d * KB + kv) ^ ((((d & 7) ^ ((d >> 2) & 7)) & 7) << 3);
}
__device__ __forceinline__ int pswz(int row, int kv) {
    return (row * KB + kv) ^ ((row & 7) << 3);
}

#define GLOAD_LDS16(gsrc, ldst)                                                     \
    __builtin_amdgcn_global_load_lds(                                               \
        (const __attribute__((address_space(1))) void*)(gsrc),                      \
        (__attribute__((address_space(3))) void*)(ldst), 16, 0, 0)

// ---- pre-pass: fp32 K,V -> bf16 swizzled tiles (once per call) ----
__global__ __launch_bounds__(256) void prep_kernel(const float* __restrict__ K,
                                                   const float* __restrict__ V,
                                                   unsigned short* __restrict__ Kp,
                                                   unsigned short* __restrict__ Vp) {
    const int tile = blockIdx.x;   // batch*NKT + t
    const int tid = threadIdx.x;
    const float* Kt = K + (size_t)tile * TILE_ELEMS;
    const float* Vt = V + (size_t)tile * TILE_ELEMS;
    unsigned short* Kd = Kp + (size_t)tile * TILE_ELEMS;
    unsigned short* Vd = Vp + (size_t)tile * TILE_ELEMS;
    #pragma unroll
    for (int i = 0; i < 4; ++i) {
        int idx = i * 256 + tid;
        int row = idx >> 4;
        int d0 = (idx & 15) << 2;
        f32x4 kf = *(const f32x4*)(Kt + row * DIM + d0);
        us4 kb = {f2bf(kf[0]), f2bf(kf[1]), f2bf(kf[2]), f2bf(kf[3])};
        *(us4*)(&Kd[kswz(row, d0)]) = kb;
    }
    // V: register 4x4 transpose
    const int dt4 = tid & 15, k4 = tid >> 4;
    f32x4 vf[4];
    #pragma unroll
    for (int rr = 0; rr < 4; ++rr)
        vf[rr] = *(const f32x4*)(Vt + (k4 * 4 + rr) * DIM + dt4 * 4);
    #pragma unroll
    for (int dd = 0; dd < 4; ++dd) {
        us4 vb = {f2bf(vf[0][dd]), f2bf(vf[1][dd]), f2bf(vf[2][dd]), f2bf(vf[3][dd])};
        *(us4*)(&Vd[vswz(dt4 * 4 + dd, k4 * 4)]) = vb;
    }
}

// ---- main flash kernel: one block = one (batch, q-tile, kv-chunk<=C tiles) ----
__global__ __launch_bounds__(256) void fa_kernel(const float* __restrict__ Q,
                                                 const unsigned short* __restrict__ Kp,
                                                 const unsigned short* __restrict__ Vp,
                                                 float* __restrict__ PO,
                                                 float* __restrict__ PM,
                                                 float* __restrict__ PL,
                                                 float* __restrict__ O,
                                                 int C, int cpb) {
    __shared__ unsigned short Klds[TILE_ELEMS];
    __shared__ unsigned short Vlds[TILE_ELEMS];
    __shared__ unsigned short Plds[4][16 * KB];

    const int tid = threadIdx.x;
    const int w = tid >> 6, lane = tid & 63, g = lane >> 4, c = lane & 15;

    // chunk decode (uniform scalar loop, <=32 iters)
    const int slot = blockIdx.x;
    const int batch = slot / cpb;
    const int c0 = slot - batch * cpb;
    int qi = 0, cum = 0;
    for (;;) {
        int nc = (qi + C) / C;        // ceil((qi+1)/C)
        if (c0 < cum + nc) break;
        cum += nc;
        ++qi;
    }
    const int sp = c0 - cum;
    const int q0 = qi * QB;
    const int nt = qi + 1;
    const int t0 = sp * C;
    const int t1 = (t0 + C < nt) ? (t0 + C) : nt;

    // Q A-fragment, pre-scaled into log2 space
    const float* Qrow = Q + (size_t)(batch * SEQ + q0 + w * 16 + c) * DIM;
    bf16x8 qa[2];
    #pragma unroll
    for (int f = 0; f < 2; ++f)
        #pragma unroll
        for (int j = 0; j < 8; ++j)
            qa[f][j] = (short)f2bf(Qrow[f * 32 + g * 8 + j] * QSCALE);

    float m[4], l[4];
    f32x4 o[4];
    #pragma unroll
    for (int r = 0; r < 4; ++r) { m[r] = -1e30f; l[r] = 0.f; }
    #pragma unroll
    for (int dt = 0; dt < 4; ++dt) o[dt] = f32x4{0.f, 0.f, 0.f, 0.f};

    for (int t = t0; t < t1; ++t) {
        __syncthreads();   // previous tile's compute done before LDS overwrite
        const char* Ksrc = (const char*)(Kp + (size_t)(batch * NKT + t) * TILE_ELEMS);
        const char* Vsrc = (const char*)(Vp + (size_t)(batch * NKT + t) * TILE_ELEMS);
        char* Kldsb = (char*)&Klds[0];
        char* Vldsb = (char*)&Vlds[0];
        #pragma unroll
        for (int i = 0; i < 2; ++i) {
            int off = (w * 2 + i) * 1024;
            GLOAD_LDS16(Ksrc + off + lane * 16, Kldsb + off);
            GLOAD_LDS16(Vsrc + off + lane * 16, Vldsb + off);
        }
        asm volatile("s_waitcnt vmcnt(0)" ::: "memory");
        __syncthreads();

        // ---- QK^T (log2-scaled): S[16 q][64 kv] per wave ----
        f32x4 s[4];
        #pragma unroll
        for (int n = 0; n < 4; ++n) {
            s[n] = f32x4{0.f, 0.f, 0.f, 0.f};
            #pragma unroll
            for (int f = 0; f < 2; ++f) {
                bf16x8 kb = *(bf16x8*)(&Klds[kswz(n * 16 + c, f * 32 + g * 8)]);
                s[n] = __builtin_amdgcn_mfma_f32_16x16x32_bf16(qa[f], kb, s[n], 0, 0, 0);
            }
        }

        // causal mask (diagonal tile only)
        if (t == nt - 1) {
            #pragma unroll
            for (int n = 0; n < 4; ++n) {
                int col = t * KB + n * 16 + c;
                #pragma unroll
                for (int r = 0; r < 4; ++r)
                    if (col > q0 + w * 16 + g * 4 + r) s[n][r] = -1e30f;
            }
        }

        // ---- online softmax in log2 space, defer-max (THR) ----
        float pmax[4];
        #pragma unroll
        for (int r = 0; r < 4; ++r) {
            float t2 = fmaxf(fmaxf(s[0][r], s[1][r]), fmaxf(s[2][r], s[3][r]));
            t2 = fmaxf(t2, __shfl_xor(t2, 1));
            t2 = fmaxf(t2, __shfl_xor(t2, 2));
            t2 = fmaxf(t2, __shfl_xor(t2, 4));
            t2 = fmaxf(t2, __shfl_xor(t2, 8));
            pmax[r] = t2;
        }
        bool need = false;
        #pragma unroll
        for (int r = 0; r < 4; ++r) need |= (pmax[r] > m[r] + THR);
        if (__any(need)) {
            #pragma unroll
            for (int r = 0; r < 4; ++r) {
                float mn = fmaxf(m[r], pmax[r]);
                float alpha = exp2f(m[r] - mn);
                m[r] = mn;
                l[r] *= alpha;
                #pragma unroll
                for (int dt = 0; dt < 4; ++dt) o[dt][r] *= alpha;
            }
        }
        float tsum[4] = {0.f, 0.f, 0.f, 0.f};
        #pragma unroll
        for (int n = 0; n < 4; ++n)
            #pragma unroll
            for (int r = 0; r < 4; ++r) {
                float pe = exp2f(s[n][r] - m[r]);
                s[n][r] = pe;
                tsum[r] += pe;
            }
        #pragma unroll
        for (int r = 0; r < 4; ++r) {
            float ts = tsum[r];
            ts += __shfl_xor(ts, 1);
            ts += __shfl_xor(ts, 2);
            ts += __shfl_xor(ts, 4);
            ts += __shfl_xor(ts, 8);
            l[r] += ts;
        }

        // ---- P (C-layout) -> per-wave LDS -> A-layout ----
        unsigned short* Pw = &Plds[w][0];
        #pragma unroll
        for (int n = 0; n < 4; ++n)
            #pragma unroll
            for (int r = 0; r < 4; ++r)
                Pw[pswz(g * 4 + r, n * 16 + c)] = f2bf(s[n][r]);
        asm volatile("s_waitcnt lgkmcnt(0)" ::: "memory");

        // ---- PV ----
        #pragma unroll
        for (int ks = 0; ks < 2; ++ks) {
            bf16x8 pa = *(bf16x8*)(&Pw[pswz(c, ks * 32 + g * 8)]);
            #pragma unroll
            for (int dt = 0; dt < 4; ++dt) {
                bf16x8 vb = *(bf16x8*)(&Vlds[vswz(dt * 16 + c, ks * 32 + g * 8)]);
                o[dt] = __builtin_amdgcn_mfma_f32_16x16x32_bf16(pa, vb, o[dt], 0, 0, 0);
            }
        }
    }

    // ---- epilogue ----
    if (nt <= C) {           // single chunk: write O directly
        #pragma unroll
        for (int r = 0; r < 4; ++r) {
            float inv = 1.f / l[r];
            float* Orow = O + (size_t)(batch * SEQ + q0 + w * 16 + g * 4 + r) * DIM;
            #pragma unroll
            for (int dt = 0; dt < 4; ++dt)
                Orow[dt * 16 + c] = o[dt][r] * inv;
        }
    } else {                 // partials at this block's own slot
        float* Pbase = PO + (size_t)slot * (QB * DIM);
        #pragma unroll
        for (int r = 0; r < 4; ++r) {
            int rowin = w * 16 + g * 4 + r;
            #pragma unroll
            for (int dt = 0; dt < 4; ++dt)
                Pbase[rowin * DIM + dt * 16 + c] = o[dt][r];
            if (c == 0) {
                PM[(size_t)slot * QB + rowin] = m[r];
                PL[(size_t)slot * QB + rowin] = l[r];
            }
        }
    }
}

__global__ __launch_bounds__(256) void combine_kernel(const float* __restrict__ PO,
                                                      const float* __restrict__ PM,
                                                      const float* __restrict__ PL,
                                                      float* __restrict__ O,
                                                      int C, int cpb) {
    const int row = blockIdx.x * 4 + (threadIdx.x >> 6);
    const int d = threadIdx.x & 63;
    const int batch = row >> 11, rr = row & 2047;
    const int qi = rr >> 6;
    const int nc = (qi + C) / C;
    if (nc == 1) return;     // fa wrote O directly
    int cum = 0;
    for (int j = 0; j < qi; ++j) cum += (j + C) / C;
    const int sb = batch * cpb + cum;
    const int rowin = rr & 63;
    float mstar = -1e30f;
    for (int sp = 0; sp < nc; ++sp)
        mstar = fmaxf(mstar, PM[(size_t)(sb + sp) * QB + rowin]);
    float ls = 0.f, os = 0.f;
    for (int sp = 0; sp < nc; ++sp) {
        float wgt = exp2f(PM[(size_t)(sb + sp) * QB + rowin] - mstar);
        ls += PL[(size_t)(sb + sp) * QB + rowin] * wgt;
        os += PO[(size_t)(sb + sp) * (QB * DIM) + rowin * DIM + d] * wgt;
    }
    O[(size_t)row * DIM + d] = os / ls;
}

extern "C" void kernel_launch(void* const* d_in, const int* in_sizes, int n_in,
                              void* d_out, int out_size, void* d_ws, size_t ws_size,
                              hipStream_t stream) {
    const float* Q = (const float*)d_in[0];
    const float* K = (const float*)d_in[1];
    const float* V = (const float*)d_in[2];
    float* O = (float*)d_out;
    (void)in_sizes; (void)n_in; (void)out_size;

    const size_t kvbytes = (size_t)BATCH * SEQ * DIM;  // elems per tensor
    const size_t base = 2 * kvbytes * sizeof(unsigned short);  // Kp + Vp = 4 MB

    int C = 2, cpb = 0;
    for (; C <= 16; ++C) {
        cpb = 0;
        for (int qi = 0; qi < NQT; ++qi) cpb += (qi + C) / C;
        size_t slots = (size_t)BATCH * cpb;
        size_t need = base + slots * ((size_t)QB * DIM + 2 * QB) * sizeof(float);
        if (need <= ws_size) break;
    }

    unsigned short* Kp = (unsigned short*)d_ws;
    unsigned short* Vp = Kp + kvbytes;
    float* PO = (float*)(Vp + kvbytes);
    float* PM = PO + (size_t)BATCH * cpb * QB * DIM;
    float* PL = PM + (size_t)BATCH * cpb * QB;

    prep_kernel<<<BATCH * NKT, 256, 0, stream>>>(K, V, Kp, Vp);
    fa_kernel<<<BATCH * cpb, 256, 0, stream>>>(Q, Kp, Vp, PO, PM, PL, O, C, cpb);
    combine_kernel<<<NROWS / 4, 256, 0, stream>>>(PO, PM, PL, O, C, cpb);
}

// Round 4
// 45.027 us; speedup vs baseline: 1.9202x; 1.4044x over previous
//
#include <hip/hip_runtime.h>
#include <hip/hip_bf16.h>

typedef __attribute__((ext_vector_type(8))) short bf16x8;
typedef __attribute__((ext_vector_type(4))) float f32x4;
typedef __attribute__((ext_vector_type(4))) unsigned short us4;

#define BATCH 8
#define SEQ 2048
#define DIM 64
#define QB 64                  // q rows per block (4 waves x 16)
#define NQT 32                 // q tiles per batch
#define NKT 32                 // kv tiles (64 rows) per batch
#define TE 4096                // elems per 64x64 tile
#define CH 8                   // kv tiles per chunk
#define CPB 80                 // chunks per batch = sum ceil((qi+1)/8)
#define QSCALE (0.125f * 1.44269504088896f)  // 1/sqrt(64) * log2(e)
#define THR 8.0f

__device__ __forceinline__ unsigned short f2bf(float f) {
    return __builtin_bit_cast(unsigned short, __float2bfloat16(f));
}

// K tile [kv][64] row-major bf16, XOR-swizzled (per 64-row tile; 64%8==0 so
// the same formula works for stacked 128-row tiles)
__device__ __forceinline__ int kswz(int row, int d) {
    return (row * DIM + d) ^ ((row & 7) << 3);
}
// V^T tile [d][64 kv]; hash mixes d&7 and d>>2 (write lanes vary d by 4,
// read lanes vary d by 1)
__device__ __forceinline__ int vswz(int d, int kv) {
    return (d * 64 + kv) ^ ((((d & 7) ^ ((d >> 2) & 7)) & 7) << 3);
}
// P tile [16 q][128 kv] per wave
__device__ __forceinline__ int pswz128(int row, int kv) {
    return (row * 128 + kv) ^ ((row & 7) << 3);
}
// chunk-prefix: number of chunks for q-tiles < qi
__device__ __forceinline__ int chunk_prefix(int qi) {
    return (qi < 8) ? qi
         : (qi < 16) ? 8 + 2 * (qi - 8)
         : (qi < 24) ? 24 + 3 * (qi - 16)
                     : 48 + 4 * (qi - 24);
}

#define GLOAD16(gsrc, ldst)                                                     \
    __builtin_amdgcn_global_load_lds(                                           \
        (const __attribute__((address_space(1))) void*)(gsrc),                  \
        (__attribute__((address_space(3))) void*)(ldst), 16, 0, 0)

#define FENCE_BARRIER_LGKM()                                   \
    do {                                                       \
        __builtin_amdgcn_sched_barrier(0);                     \
        asm volatile("s_waitcnt lgkmcnt(0)" ::: "memory");     \
        __builtin_amdgcn_s_barrier();                          \
        __builtin_amdgcn_sched_barrier(0);                     \
    } while (0)

#define FENCE_BARRIER_ALL()                                            \
    do {                                                               \
        __builtin_amdgcn_sched_barrier(0);                             \
        asm volatile("s_waitcnt vmcnt(0) lgkmcnt(0)" ::: "memory");    \
        __builtin_amdgcn_s_barrier();                                  \
        __builtin_amdgcn_sched_barrier(0);                             \
    } while (0)

// ---- pre-pass: fp32 K,V -> bf16 swizzled tiles ----
__global__ __launch_bounds__(256) void prep_kernel(const float* __restrict__ K,
                                                   const float* __restrict__ V,
                                                   unsigned short* __restrict__ Kp,
                                                   unsigned short* __restrict__ Vp) {
    const int tile = blockIdx.x;
    const int tid = threadIdx.x;
    const float* Kt = K + (size_t)tile * TE;
    const float* Vt = V + (size_t)tile * TE;
    unsigned short* Kd = Kp + (size_t)tile * TE;
    unsigned short* Vd = Vp + (size_t)tile * TE;
    #pragma unroll
    for (int i = 0; i < 4; ++i) {
        int idx = i * 256 + tid;
        int row = idx >> 4;
        int d0 = (idx & 15) << 2;
        f32x4 kf = *(const f32x4*)(Kt + row * DIM + d0);
        us4 kb = {f2bf(kf[0]), f2bf(kf[1]), f2bf(kf[2]), f2bf(kf[3])};
        *(us4*)(&Kd[kswz(row, d0)]) = kb;
    }
    const int dt4 = tid & 15, k4 = tid >> 4;
    f32x4 vf[4];
    #pragma unroll
    for (int rr = 0; rr < 4; ++rr)
        vf[rr] = *(const f32x4*)(Vt + (k4 * 4 + rr) * DIM + dt4 * 4);
    #pragma unroll
    for (int dd = 0; dd < 4; ++dd) {
        us4 vb = {f2bf(vf[0][dd]), f2bf(vf[1][dd]), f2bf(vf[2][dd]), f2bf(vf[3][dd])};
        *(us4*)(&Vd[vswz(dt4 * 4 + dd, k4 * 4)]) = vb;
    }
}

// ---- main flash kernel: block = (batch, q-tile, chunk of <=8 kv-tiles) ----
__global__ __launch_bounds__(256) void fa_kernel(const float* __restrict__ Q,
                                                 const unsigned short* __restrict__ Kp,
                                                 const unsigned short* __restrict__ Vp,
                                                 float* __restrict__ PO,
                                                 float* __restrict__ PM,
                                                 float* __restrict__ PL,
                                                 float* __restrict__ O) {
    __shared__ unsigned short KL[2][8192];   // [buf][128 kv x 64 d]; P overlays spent buf
    __shared__ unsigned short VL[2][8192];   // [buf][2 x (64 d x 64 kv)]

    const int tid = threadIdx.x;
    const int w = tid >> 6, lane = tid & 63, g = lane >> 4, c = lane & 15;

    // decode: big chunks first
    const int slot = blockIdx.x;
    const int batch = slot & 7;
    const int c0 = (CPB - 1) - (slot >> 3);
    int qi, sp;
    if (c0 < 8)        { qi = c0; sp = 0; }
    else if (c0 < 24)  { int x = c0 - 8;  qi = 8 + (x >> 1); sp = x & 1; }
    else if (c0 < 48)  { int x = c0 - 24; int q = x / 3; qi = 16 + q; sp = x - 3 * q; }
    else               { int x = c0 - 48; qi = 24 + (x >> 2); sp = x & 3; }

    const int q0 = qi * QB;
    const int nt = qi + 1;
    const int t0 = sp * CH;
    const int t1 = (t0 + CH < nt) ? (t0 + CH) : nt;
    const int tiles = t1 - t0;
    const int nu = (tiles + 1) >> 1;
    const bool dchunk = (t1 == nt);

    const unsigned short* Kb = Kp + (size_t)batch * NKT * TE;
    const unsigned short* Vb = Vp + (size_t)batch * NKT * TE;

    // stage unit 0
    {
        int tA = t0;
        bool two0 = (t0 + 1 < t1);
        const char* Ks = (const char*)(Kb + (size_t)tA * TE);
        const char* Vs = (const char*)(Vb + (size_t)tA * TE);
        char* kd = (char*)&KL[0][0];
        char* vd = (char*)&VL[0][0];
        if (two0) {
            #pragma unroll
            for (int i = 0; i < 4; ++i) {
                int off = (w * 4 + i) * 1024;
                GLOAD16(Ks + off + lane * 16, kd + off);
                GLOAD16(Vs + off + lane * 16, vd + off);
            }
        } else {
            #pragma unroll
            for (int i = 0; i < 2; ++i) {
                int off = (w * 2 + i) * 1024;
                GLOAD16(Ks + off + lane * 16, kd + off);
                GLOAD16(Vs + off + lane * 16, vd + off);
            }
        }
    }

    // Q fragments (overlap with staging)
    const float* Qrow = Q + (size_t)(batch * SEQ + q0 + w * 16 + c) * DIM;
    f32x4 qf0 = *(const f32x4*)(Qrow + g * 8);
    f32x4 qf1 = *(const f32x4*)(Qrow + g * 8 + 4);
    f32x4 qf2 = *(const f32x4*)(Qrow + 32 + g * 8);
    f32x4 qf3 = *(const f32x4*)(Qrow + 32 + g * 8 + 4);
    bf16x8 qa[2];
    #pragma unroll
    for (int j = 0; j < 4; ++j) {
        qa[0][j]     = (short)f2bf(qf0[j] * QSCALE);
        qa[0][j + 4] = (short)f2bf(qf1[j] * QSCALE);
        qa[1][j]     = (short)f2bf(qf2[j] * QSCALE);
        qa[1][j + 4] = (short)f2bf(qf3[j] * QSCALE);
    }

    float m[4], l[4];
    f32x4 o[4];
    #pragma unroll
    for (int r = 0; r < 4; ++r) { m[r] = -1e30f; l[r] = 0.f; }
    #pragma unroll
    for (int dt = 0; dt < 4; ++dt) o[dt] = f32x4{0.f, 0.f, 0.f, 0.f};

    FENCE_BARRIER_ALL();   // unit 0 staged

    for (int u = 0; u < nu; ++u) {
        const int cb = u & 1;
        const bool last = (u == nu - 1);
        const bool single = last && (tiles & 1);
        const bool dmask = last && dchunk;

        // prefetch next unit (stays in flight across the mid barrier)
        if (!last) {
            int tA = t0 + 2 * (u + 1);
            bool two = (tA + 1 < t1);
            const char* Ks = (const char*)(Kb + (size_t)tA * TE);
            const char* Vs = (const char*)(Vb + (size_t)tA * TE);
            char* kd = (char*)&KL[cb ^ 1][0];
            char* vd = (char*)&VL[cb ^ 1][0];
            if (two) {
                #pragma unroll
                for (int i = 0; i < 4; ++i) {
                    int off = (w * 4 + i) * 1024;
                    GLOAD16(Ks + off + lane * 16, kd + off);
                    GLOAD16(Vs + off + lane * 16, vd + off);
                }
            } else {
                #pragma unroll
                for (int i = 0; i < 2; ++i) {
                    int off = (w * 2 + i) * 1024;
                    GLOAD16(Ks + off + lane * 16, kd + off);
                    GLOAD16(Vs + off + lane * 16, vd + off);
                }
            }
        }

        // ---- QK^T: S[16 q][128 kv] ----
        f32x4 s[8];
        #pragma unroll
        for (int n = 0; n < 8; ++n) s[n] = f32x4{0.f, 0.f, 0.f, 0.f};
        __builtin_amdgcn_s_setprio(1);
        #pragma unroll
        for (int n = 0; n < 4; ++n)
            #pragma unroll
            for (int f = 0; f < 2; ++f) {
                int row = n * 16 + c;
                bf16x8 kb = *(bf16x8*)(&KL[cb][kswz(row, f * 32 + g * 8)]);
                s[n] = __builtin_amdgcn_mfma_f32_16x16x32_bf16(qa[f], kb, s[n], 0, 0, 0);
            }
        if (!single) {
            #pragma unroll
            for (int n = 0; n < 4; ++n)
                #pragma unroll
                for (int f = 0; f < 2; ++f) {
                    int row = (n + 4) * 16 + c;
                    bf16x8 kb = *(bf16x8*)(&KL[cb][kswz(row, f * 32 + g * 8)]);
                    s[n + 4] = __builtin_amdgcn_mfma_f32_16x16x32_bf16(qa[f], kb, s[n + 4], 0, 0, 0);
                }
        }
        __builtin_amdgcn_s_setprio(0);
        if (single) {
            #pragma unroll
            for (int n = 4; n < 8; ++n) s[n] = f32x4{-1e30f, -1e30f, -1e30f, -1e30f};
        }
        if (dmask) {
            const int dbase = (t1 - 1) * 64;
            if (single) {
                #pragma unroll
                for (int n = 0; n < 4; ++n) {
                    int col = dbase + n * 16 + c;
                    #pragma unroll
                    for (int r = 0; r < 4; ++r)
                        if (col > q0 + w * 16 + g * 4 + r) s[n][r] = -1e30f;
                }
            } else {
                #pragma unroll
                for (int n = 0; n < 4; ++n) {
                    int col = dbase + n * 16 + c;
                    #pragma unroll
                    for (int r = 0; r < 4; ++r)
                        if (col > q0 + w * 16 + g * 4 + r) s[n + 4][r] = -1e30f;
                }
            }
        }

        FENCE_BARRIER_LGKM();   // all waves done reading K[cb]; vmcnt NOT drained

        // ---- online softmax (log2 space, defer-max) ----
        float pmax[4];
        #pragma unroll
        for (int r = 0; r < 4; ++r) {
            float t2 = fmaxf(fmaxf(fmaxf(s[0][r], s[1][r]), fmaxf(s[2][r], s[3][r])),
                             fmaxf(fmaxf(s[4][r], s[5][r]), fmaxf(s[6][r], s[7][r])));
            t2 = fmaxf(t2, __shfl_xor(t2, 1));
            t2 = fmaxf(t2, __shfl_xor(t2, 2));
            t2 = fmaxf(t2, __shfl_xor(t2, 4));
            t2 = fmaxf(t2, __shfl_xor(t2, 8));
            pmax[r] = t2;
        }
        bool need = false;
        #pragma unroll
        for (int r = 0; r < 4; ++r) need |= (pmax[r] > m[r] + THR);
        if (__any(need)) {
            #pragma unroll
            for (int r = 0; r < 4; ++r) {
                float mn = fmaxf(m[r], pmax[r]);
                float alpha = exp2f(m[r] - mn);
                m[r] = mn;
                l[r] *= alpha;
                #pragma unroll
                for (int dt = 0; dt < 4; ++dt) o[dt][r] *= alpha;
            }
        }
        float tsum[4] = {0.f, 0.f, 0.f, 0.f};
        #pragma unroll
        for (int n = 0; n < 8; ++n)
            #pragma unroll
            for (int r = 0; r < 4; ++r) {
                float pe = exp2f(s[n][r] - m[r]);
                s[n][r] = pe;
                tsum[r] += pe;
            }
        #pragma unroll
        for (int r = 0; r < 4; ++r) {
            float ts = tsum[r];
            ts += __shfl_xor(ts, 1);
            ts += __shfl_xor(ts, 2);
            ts += __shfl_xor(ts, 4);
            ts += __shfl_xor(ts, 8);
            l[r] += ts;
        }

        // ---- P -> LDS (overlay on K[cb]); each wave its own 2048-elem region ----
        unsigned short* Pw = &KL[cb][w * 2048];
        #pragma unroll
        for (int n = 0; n < 8; ++n)
            #pragma unroll
            for (int r = 0; r < 4; ++r)
                Pw[pswz128(g * 4 + r, n * 16 + c)] = f2bf(s[n][r]);
        asm volatile("s_waitcnt lgkmcnt(0)" ::: "memory");
        __builtin_amdgcn_sched_barrier(0);

        // ---- PV: O += P[16][128] * V[128][64] ----
        __builtin_amdgcn_s_setprio(1);
        #pragma unroll
        for (int ks = 0; ks < 2; ++ks) {
            bf16x8 pa = *(bf16x8*)(&Pw[pswz128(c, ks * 32 + g * 8)]);
            #pragma unroll
            for (int dt = 0; dt < 4; ++dt) {
                int d = dt * 16 + c;
                bf16x8 vb = *(bf16x8*)(&VL[cb][vswz(d, ks * 32 + g * 8)]);
                o[dt] = __builtin_amdgcn_mfma_f32_16x16x32_bf16(pa, vb, o[dt], 0, 0, 0);
            }
        }
        if (!single) {
            #pragma unroll
            for (int ks = 0; ks < 2; ++ks) {
                bf16x8 pa = *(bf16x8*)(&Pw[pswz128(c, 64 + ks * 32 + g * 8)]);
                #pragma unroll
                for (int dt = 0; dt < 4; ++dt) {
                    int d = dt * 16 + c;
                    bf16x8 vb = *(bf16x8*)(&VL[cb][4096 + vswz(d, ks * 32 + g * 8)]);
                    o[dt] = __builtin_amdgcn_mfma_f32_16x16x32_bf16(pa, vb, o[dt], 0, 0, 0);
                }
            }
        }
        __builtin_amdgcn_s_setprio(0);

        if (!last) FENCE_BARRIER_ALL();   // next unit staged + everyone past PV
    }

    // ---- epilogue ----
    if (nt <= CH) {
        #pragma unroll
        for (int r = 0; r < 4; ++r) {
            float inv = 1.f / l[r];
            float* Orow = O + (size_t)(batch * SEQ + q0 + w * 16 + g * 4 + r) * DIM;
            #pragma unroll
            for (int dt = 0; dt < 4; ++dt)
                Orow[dt * 16 + c] = o[dt][r] * inv;
        }
    } else {
        float* Pbase = PO + (size_t)slot * (QB * DIM);
        #pragma unroll
        for (int r = 0; r < 4; ++r) {
            int rowin = w * 16 + g * 4 + r;
            #pragma unroll
            for (int dt = 0; dt < 4; ++dt)
                Pbase[rowin * DIM + dt * 16 + c] = o[dt][r];
            if (c == 0) {
                PM[(size_t)slot * QB + rowin] = m[r];
                PL[(size_t)slot * QB + rowin] = l[r];
            }
        }
    }
}

// ---- combine (only q-tiles with qi>=8), vectorized f32x4 ----
__global__ __launch_bounds__(256) void combine_kernel(const float* __restrict__ PO,
                                                      const float* __restrict__ PM,
                                                      const float* __restrict__ PL,
                                                      float* __restrict__ O) {
    const int tid = threadIdx.x;
    const int ridx = blockIdx.x * 16 + (tid >> 4);
    const int d0 = (tid & 15) << 2;
    const int batch = ridx / 1536;          // 24 q-tiles x 64 rows
    const int rem = ridx - batch * 1536;
    const int qi = 8 + (rem >> 6);
    const int rowin = rem & 63;
    const int nc = (qi + CH) >> 3;          // ceil((qi+1)/8)
    const int pfx = chunk_prefix(qi);

    float mstar = -1e30f;
    #pragma unroll 4
    for (int sp = 0; sp < nc; ++sp) {
        int slot = ((CPB - 1 - (pfx + sp)) << 3) | batch;
        mstar = fmaxf(mstar, PM[(size_t)slot * QB + rowin]);
    }
    float ls = 0.f;
    f32x4 os = {0.f, 0.f, 0.f, 0.f};
    #pragma unroll 4
    for (int sp = 0; sp < nc; ++sp) {
        int slot = ((CPB - 1 - (pfx + sp)) << 3) | batch;
        float wgt = exp2f(PM[(size_t)slot * QB + rowin] - mstar);
        ls += PL[(size_t)slot * QB + rowin] * wgt;
        f32x4 po = *(const f32x4*)(PO + (size_t)slot * (QB * DIM) + rowin * DIM + d0);
        os += po * wgt;
    }
    const int grow = batch * SEQ + qi * 64 + rowin;
    float inv = 1.f / ls;
    f32x4 res = os * inv;
    *(f32x4*)(O + (size_t)grow * DIM + d0) = res;
}

extern "C" void kernel_launch(void* const* d_in, const int* in_sizes, int n_in,
                              void* d_out, int out_size, void* d_ws, size_t ws_size,
                              hipStream_t stream) {
    const float* Q = (const float*)d_in[0];
    const float* K = (const float*)d_in[1];
    const float* V = (const float*)d_in[2];
    float* O = (float*)d_out;
    (void)in_sizes; (void)n_in; (void)out_size; (void)ws_size;

    const size_t kvelems = (size_t)BATCH * SEQ * DIM;
    unsigned short* Kp = (unsigned short*)d_ws;
    unsigned short* Vp = Kp + kvelems;
    float* PO = (float*)(Vp + kvelems);
    float* PM = PO + (size_t)BATCH * CPB * QB * DIM;
    float* PL = PM + (size_t)BATCH * CPB * QB;

    prep_kernel<<<BATCH * NKT, 256, 0, stream>>>(K, V, Kp, Vp);
    fa_kernel<<<BATCH * CPB, 256, 0, stream>>>(Q, Kp, Vp, PO, PM, PL, O);
    combine_kernel<<<BATCH * 24 * 64 / 16, 256, 0, stream>>>(PO, PM, PL, O);
}

// Round 5
// 42.030 us; speedup vs baseline: 2.0571x; 1.0713x over previous
//
#include <hip/hip_runtime.h>
#include <hip/hip_bf16.h>

typedef __attribute__((ext_vector_type(8))) short bf16x8;
typedef __attribute__((ext_vector_type(4))) float f32x4;
typedef __attribute__((ext_vector_type(4))) unsigned short us4;

#define BATCH 8
#define SEQ 2048
#define DIM 64
#define QB 64                  // q rows per block (4 waves x 16)
#define NQT 32
#define NKT 32
#define TE 4096                // elems per 64x64 tile
#define CH 8                   // kv tiles per chunk
#define CPB 80                 // chunks per batch = sum ceil((qi+1)/8)
#define QSCALE (0.125f * 1.44269504088896f)  // 1/sqrt(64) * log2(e)
#define THR 8.0f

__device__ __forceinline__ unsigned short f2bf(float f) {
    return __builtin_bit_cast(unsigned short, __float2bfloat16(f));
}

// K tile [kv][64] row-major bf16, XOR-swizzled
__device__ __forceinline__ int kswz(int row, int d) {
    return (row * DIM + d) ^ ((row & 7) << 3);
}
// V^T tile [d][64 kv]; hash mixes d&7 and d>>2
__device__ __forceinline__ int vswz(int d, int kv) {
    return (d * 64 + kv) ^ ((((d & 7) ^ ((d >> 2) & 7)) & 7) << 3);
}
// P tile [16 q][64 kv] per wave
__device__ __forceinline__ int pswz(int row, int kv) {
    return (row * 64 + kv) ^ ((row & 7) << 3);
}
__device__ __forceinline__ int chunk_prefix(int qi) {
    return (qi < 8) ? qi
         : (qi < 16) ? 8 + 2 * (qi - 8)
         : (qi < 24) ? 24 + 3 * (qi - 16)
                     : 48 + 4 * (qi - 24);
}

#define GLOAD16(gsrc, ldst)                                                     \
    __builtin_amdgcn_global_load_lds(                                           \
        (const __attribute__((address_space(1))) void*)(gsrc),                  \
        (__attribute__((address_space(3))) void*)(ldst), 16, 0, 0)

// ---- pre-pass: fp32 K,V -> bf16 swizzled tiles; blockIdx&7 = batch (XCD match) ----
__global__ __launch_bounds__(256) void prep_kernel(const float* __restrict__ K,
                                                   const float* __restrict__ V,
                                                   unsigned short* __restrict__ Kp,
                                                   unsigned short* __restrict__ Vp) {
    const int batch = blockIdx.x & 7;
    const int t = blockIdx.x >> 3;
    const int tile = batch * NKT + t;
    const int tid = threadIdx.x;
    const float* Kt = K + (size_t)tile * TE;
    const float* Vt = V + (size_t)tile * TE;
    unsigned short* Kd = Kp + (size_t)tile * TE;
    unsigned short* Vd = Vp + (size_t)tile * TE;
    #pragma unroll
    for (int i = 0; i < 4; ++i) {
        int idx = i * 256 + tid;
        int row = idx >> 4;
        int d0 = (idx & 15) << 2;
        f32x4 kf = *(const f32x4*)(Kt + row * DIM + d0);
        us4 kb = {f2bf(kf[0]), f2bf(kf[1]), f2bf(kf[2]), f2bf(kf[3])};
        *(us4*)(&Kd[kswz(row, d0)]) = kb;
    }
    const int dt4 = tid & 15, k4 = tid >> 4;
    f32x4 vf[4];
    #pragma unroll
    for (int rr = 0; rr < 4; ++rr)
        vf[rr] = *(const f32x4*)(Vt + (k4 * 4 + rr) * DIM + dt4 * 4);
    #pragma unroll
    for (int dd = 0; dd < 4; ++dd) {
        us4 vb = {f2bf(vf[0][dd]), f2bf(vf[1][dd]), f2bf(vf[2][dd]), f2bf(vf[3][dd])};
        *(us4*)(&Vd[vswz(dt4 * 4 + dd, k4 * 4)]) = vb;
    }
}

// ---- main flash kernel: block = (batch, q-tile, chunk of <=8 kv-tiles) ----
__global__ __launch_bounds__(256, 4) void fa_kernel(const float* __restrict__ Q,
                                                    const unsigned short* __restrict__ Kp,
                                                    const unsigned short* __restrict__ Vp,
                                                    float* __restrict__ PO,
                                                    float* __restrict__ PM,
                                                    float* __restrict__ PL,
                                                    float* __restrict__ O) {
    __shared__ unsigned short KL[2][4096];   // [buf][64 kv x 64 d]
    __shared__ unsigned short VL[2][4096];   // [buf][64 d x 64 kv]
    __shared__ unsigned short PB[4][1024];   // per-wave P [16 q][64 kv]

    const int tid = threadIdx.x;
    const int w = tid >> 6, lane = tid & 63, g = lane >> 4, c = lane & 15;

    // decode: big chunks first; batch = slot&7 pins batch -> XCD
    const int slot = blockIdx.x;
    const int batch = slot & 7;
    const int c0 = (CPB - 1) - (slot >> 3);
    int qi, sp;
    if (c0 < 8)        { qi = c0; sp = 0; }
    else if (c0 < 24)  { int x = c0 - 8;  qi = 8 + (x >> 1); sp = x & 1; }
    else if (c0 < 48)  { int x = c0 - 24; int q = x / 3; qi = 16 + q; sp = x - 3 * q; }
    else               { int x = c0 - 48; qi = 24 + (x >> 2); sp = x & 3; }

    const int q0 = qi * QB;
    const int nt = qi + 1;
    const int t0 = sp * CH;
    const int t1 = (t0 + CH < nt) ? (t0 + CH) : nt;
    const int tiles = t1 - t0;
    const bool dchunk = (t1 == nt);

    const unsigned short* Kb = Kp + (size_t)batch * NKT * TE;
    const unsigned short* Vb = Vp + (size_t)batch * NKT * TE;

#define STAGE_TILE(tidx, buf)                                          \
    do {                                                               \
        const char* Ks_ = (const char*)(Kb + (size_t)(tidx) * TE);     \
        const char* Vs_ = (const char*)(Vb + (size_t)(tidx) * TE);     \
        char* kd_ = (char*)&KL[buf][0];                                \
        char* vd_ = (char*)&VL[buf][0];                                \
        _Pragma("unroll")                                              \
        for (int i_ = 0; i_ < 2; ++i_) {                               \
            int off_ = (w * 2 + i_) * 1024;                            \
            GLOAD16(Ks_ + off_ + lane * 16, kd_ + off_);               \
            GLOAD16(Vs_ + off_ + lane * 16, vd_ + off_);               \
        }                                                              \
    } while (0)

    STAGE_TILE(t0, 0);

    // Q fragments (overlap with staging)
    const float* Qrow = Q + (size_t)(batch * SEQ + q0 + w * 16 + c) * DIM;
    f32x4 qf0 = *(const f32x4*)(Qrow + g * 8);
    f32x4 qf1 = *(const f32x4*)(Qrow + g * 8 + 4);
    f32x4 qf2 = *(const f32x4*)(Qrow + 32 + g * 8);
    f32x4 qf3 = *(const f32x4*)(Qrow + 32 + g * 8 + 4);
    bf16x8 qa[2];
    #pragma unroll
    for (int j = 0; j < 4; ++j) {
        qa[0][j]     = (short)f2bf(qf0[j] * QSCALE);
        qa[0][j + 4] = (short)f2bf(qf1[j] * QSCALE);
        qa[1][j]     = (short)f2bf(qf2[j] * QSCALE);
        qa[1][j + 4] = (short)f2bf(qf3[j] * QSCALE);
    }

    float m[4], l[4];
    f32x4 o[4];
    #pragma unroll
    for (int r = 0; r < 4; ++r) { m[r] = -1e30f; l[r] = 0.f; }
    #pragma unroll
    for (int dt = 0; dt < 4; ++dt) o[dt] = f32x4{0.f, 0.f, 0.f, 0.f};

    __builtin_amdgcn_sched_barrier(0);
    asm volatile("s_waitcnt vmcnt(0)" ::: "memory");
    __builtin_amdgcn_s_barrier();
    __builtin_amdgcn_sched_barrier(0);

    for (int u = 0; u < tiles; ++u) {
        const int cb = u & 1;
        const bool last = (u == tiles - 1);

        // prefetch next tile (stays in flight through this unit's compute)
        if (!last) STAGE_TILE(t0 + u + 1, cb ^ 1);

        // ---- QK^T: S[16 q][64 kv] ----
        f32x4 s[4];
        #pragma unroll
        for (int n = 0; n < 4; ++n) s[n] = f32x4{0.f, 0.f, 0.f, 0.f};
        __builtin_amdgcn_s_setprio(1);
        #pragma unroll
        for (int n = 0; n < 4; ++n)
            #pragma unroll
            for (int f = 0; f < 2; ++f) {
                bf16x8 kb = *(bf16x8*)(&KL[cb][kswz(n * 16 + c, f * 32 + g * 8)]);
                s[n] = __builtin_amdgcn_mfma_f32_16x16x32_bf16(qa[f], kb, s[n], 0, 0, 0);
            }
        __builtin_amdgcn_s_setprio(0);

        // causal mask (diagonal tile only)
        if (dchunk && last) {
            const int dbase = (nt - 1) * 64;
            #pragma unroll
            for (int n = 0; n < 4; ++n) {
                int col = dbase + n * 16 + c;
                #pragma unroll
                for (int r = 0; r < 4; ++r)
                    if (col > q0 + w * 16 + g * 4 + r) s[n][r] = -1e30f;
            }
        }

        // ---- online softmax (log2 space, defer-max) ----
        float pmax[4];
        #pragma unroll
        for (int r = 0; r < 4; ++r) {
            float t2 = fmaxf(fmaxf(s[0][r], s[1][r]), fmaxf(s[2][r], s[3][r]));
            t2 = fmaxf(t2, __shfl_xor(t2, 1));
            t2 = fmaxf(t2, __shfl_xor(t2, 2));
            t2 = fmaxf(t2, __shfl_xor(t2, 4));
            t2 = fmaxf(t2, __shfl_xor(t2, 8));
            pmax[r] = t2;
        }
        bool need = false;
        #pragma unroll
        for (int r = 0; r < 4; ++r) need |= (pmax[r] > m[r] + THR);
        if (__any(need)) {
            #pragma unroll
            for (int r = 0; r < 4; ++r) {
                float mn = fmaxf(m[r], pmax[r]);
                float alpha = exp2f(m[r] - mn);
                m[r] = mn;
                l[r] *= alpha;
                #pragma unroll
                for (int dt = 0; dt < 4; ++dt) o[dt][r] *= alpha;
            }
        }
        float tsum[4] = {0.f, 0.f, 0.f, 0.f};
        #pragma unroll
        for (int n = 0; n < 4; ++n)
            #pragma unroll
            for (int r = 0; r < 4; ++r) {
                float pe = exp2f(s[n][r] - m[r]);
                s[n][r] = pe;
                tsum[r] += pe;
            }
        #pragma unroll
        for (int r = 0; r < 4; ++r) {
            float ts = tsum[r];
            ts += __shfl_xor(ts, 1);
            ts += __shfl_xor(ts, 2);
            ts += __shfl_xor(ts, 4);
            ts += __shfl_xor(ts, 8);
            l[r] += ts;
        }

        // ---- P -> own wave LDS region (no barrier: wave-local hazard) ----
        unsigned short* Pw = &PB[w][0];
        #pragma unroll
        for (int n = 0; n < 4; ++n)
            #pragma unroll
            for (int r = 0; r < 4; ++r)
                Pw[pswz(g * 4 + r, n * 16 + c)] = f2bf(s[n][r]);
        asm volatile("s_waitcnt lgkmcnt(0)" ::: "memory");
        __builtin_amdgcn_sched_barrier(0);

        // ---- PV: O += P[16][64] * V[64][64] ----
        __builtin_amdgcn_s_setprio(1);
        #pragma unroll
        for (int ks = 0; ks < 2; ++ks) {
            bf16x8 pa = *(bf16x8*)(&Pw[pswz(c, ks * 32 + g * 8)]);
            #pragma unroll
            for (int dt = 0; dt < 4; ++dt) {
                bf16x8 vb = *(bf16x8*)(&VL[cb][vswz(dt * 16 + c, ks * 32 + g * 8)]);
                o[dt] = __builtin_amdgcn_mfma_f32_16x16x32_bf16(pa, vb, o[dt], 0, 0, 0);
            }
        }
        __builtin_amdgcn_s_setprio(0);

        // next unit staged + all waves past this unit's K/V reads
        if (!last) {
            __builtin_amdgcn_sched_barrier(0);
            asm volatile("s_waitcnt vmcnt(0)" ::: "memory");
            __builtin_amdgcn_s_barrier();
            __builtin_amdgcn_sched_barrier(0);
        }
    }

    // ---- epilogue ----
    if (nt <= CH) {
        #pragma unroll
        for (int r = 0; r < 4; ++r) {
            float inv = 1.f / l[r];
            float* Orow = O + (size_t)(batch * SEQ + q0 + w * 16 + g * 4 + r) * DIM;
            #pragma unroll
            for (int dt = 0; dt < 4; ++dt)
                Orow[dt * 16 + c] = o[dt][r] * inv;
        }
    } else {
        float* Pbase = PO + (size_t)slot * (QB * DIM);
        #pragma unroll
        for (int r = 0; r < 4; ++r) {
            int rowin = w * 16 + g * 4 + r;
            #pragma unroll
            for (int dt = 0; dt < 4; ++dt)
                Pbase[rowin * DIM + dt * 16 + c] = o[dt][r];
            if (c == 0) {
                PM[(size_t)slot * QB + rowin] = m[r];
                PL[(size_t)slot * QB + rowin] = l[r];
            }
        }
    }
#undef STAGE_TILE
}

// ---- combine (q-tiles with qi>=8), vectorized f32x4 ----
__global__ __launch_bounds__(256) void combine_kernel(const float* __restrict__ PO,
                                                      const float* __restrict__ PM,
                                                      const float* __restrict__ PL,
                                                      float* __restrict__ O) {
    const int tid = threadIdx.x;
    const int ridx = blockIdx.x * 16 + (tid >> 4);
    const int d0 = (tid & 15) << 2;
    const int batch = ridx / 1536;
    const int rem = ridx - batch * 1536;
    const int qi = 8 + (rem >> 6);
    const int rowin = rem & 63;
    const int nc = (qi + CH) >> 3;
    const int pfx = chunk_prefix(qi);

    float mstar = -1e30f;
    #pragma unroll 4
    for (int sp = 0; sp < nc; ++sp) {
        int slot = ((CPB - 1 - (pfx + sp)) << 3) | batch;
        mstar = fmaxf(mstar, PM[(size_t)slot * QB + rowin]);
    }
    float ls = 0.f;
    f32x4 os = {0.f, 0.f, 0.f, 0.f};
    #pragma unroll 4
    for (int sp = 0; sp < nc; ++sp) {
        int slot = ((CPB - 1 - (pfx + sp)) << 3) | batch;
        float wgt = exp2f(PM[(size_t)slot * QB + rowin] - mstar);
        ls += PL[(size_t)slot * QB + rowin] * wgt;
        f32x4 po = *(const f32x4*)(PO + (size_t)slot * (QB * DIM) + rowin * DIM + d0);
        os += po * wgt;
    }
    const int grow = batch * SEQ + qi * 64 + rowin;
    float inv = 1.f / ls;
    f32x4 res = os * inv;
    *(f32x4*)(O + (size_t)grow * DIM + d0) = res;
}

extern "C" void kernel_launch(void* const* d_in, const int* in_sizes, int n_in,
                              void* d_out, int out_size, void* d_ws, size_t ws_size,
                              hipStream_t stream) {
    const float* Q = (const float*)d_in[0];
    const float* K = (const float*)d_in[1];
    const float* V = (const float*)d_in[2];
    float* O = (float*)d_out;
    (void)in_sizes; (void)n_in; (void)out_size; (void)ws_size;

    const size_t kvelems = (size_t)BATCH * SEQ * DIM;
    unsigned short* Kp = (unsigned short*)d_ws;
    unsigned short* Vp = Kp + kvelems;
    float* PO = (float*)(Vp + kvelems);
    float* PM = PO + (size_t)BATCH * CPB * QB * DIM;
    float* PL = PM + (size_t)BATCH * CPB * QB;

    prep_kernel<<<BATCH * NKT, 256, 0, stream>>>(K, V, Kp, Vp);
    fa_kernel<<<BATCH * CPB, 256, 0, stream>>>(Q, Kp, Vp, PO, PM, PL, O);
    combine_kernel<<<BATCH * 24 * 64 / 16, 256, 0, stream>>>(PO, PM, PL, O);
}